// Round 1
// baseline (144.113 us; speedup 1.0000x reference)
//
#include <hip/hip_runtime.h>
#include <math.h>

#define K_COMP 128
#define LOG2E 1.4426950408889634f
#define INV_SQRT_2PI 0.3989422804014327f

// Prep: softmax(pi_l), then per-component {mu, a = -0.5*exp(-lv)*log2(e),
// lc = log2(pi_k * inv_sqrt_2pi * exp(-0.5*lv))} packed as float4 into ws.
// One wave (64 threads), each handles 2 components.
__global__ void gmm_prep(const float* __restrict__ pi_l,
                         const float* __restrict__ mu,
                         const float* __restrict__ lv,
                         float4* __restrict__ params) {
    int t = threadIdx.x;                 // 0..63
    float p0 = pi_l[t];
    float p1 = pi_l[t + 64];
    float m = fmaxf(p0, p1);
    #pragma unroll
    for (int off = 1; off < 64; off <<= 1)
        m = fmaxf(m, __shfl_xor(m, off, 64));
    float e0 = expf(p0 - m);
    float e1 = expf(p1 - m);
    float s = e0 + e1;
    #pragma unroll
    for (int off = 1; off < 64; off <<= 1)
        s += __shfl_xor(s, off, 64);
    float inv_s = 1.0f / s;
    #pragma unroll
    for (int j = 0; j < 2; j++) {
        int k = t + 64 * j;
        float e = (j == 0) ? e0 : e1;
        float pi_k = e * inv_s;
        float lvk = lv[k];
        float inv_var = expf(-lvk);
        float coef = pi_k * INV_SQRT_2PI * expf(-0.5f * lvk);
        float a = -0.5f * inv_var * LOG2E;
        float lc = log2f(coef);          // coef==0 -> -inf -> exp2 -> 0, safe
        params[k] = make_float4(mu[k], a, lc, 0.0f);
    }
}

// Main: each thread evaluates 8 points against all 128 components.
// prob[n] = sum_k exp2( (x-mu_k)^2 * a_k + lc_k )
__global__ __launch_bounds__(256) void gmm_main(const float* __restrict__ mz,
                                                const float4* __restrict__ params,
                                                float* __restrict__ out,
                                                int n) {
    __shared__ float4 sp[K_COMP];
    int tid = threadIdx.x;
    if (tid < K_COMP) sp[tid] = params[tid];
    __syncthreads();

    long gid = (long)blockIdx.x * blockDim.x + tid;
    long base = gid * 8;
    if (base >= n) return;

    const float4* mz4 = (const float4*)mz;
    float4 x01 = mz4[gid * 2];
    float4 x23 = mz4[gid * 2 + 1];
    float x[8] = {x01.x, x01.y, x01.z, x01.w, x23.x, x23.y, x23.z, x23.w};
    float acc[8] = {0.f, 0.f, 0.f, 0.f, 0.f, 0.f, 0.f, 0.f};

    #pragma unroll 4
    for (int k = 0; k < K_COMP; k++) {
        float4 p = sp[k];                // ds_read_b128, broadcast (free)
        #pragma unroll
        for (int j = 0; j < 8; j++) {
            float d  = x[j] - p.x;       // v_sub_f32
            float da = d * p.y;          // v_mul_f32
            float t  = __builtin_fmaf(da, d, p.z);  // v_fma_f32
            acc[j] += __builtin_amdgcn_exp2f(t);    // v_exp_f32 + v_add_f32
        }
    }

    float4* out4 = (float4*)out;
    out4[gid * 2]     = make_float4(acc[0], acc[1], acc[2], acc[3]);
    out4[gid * 2 + 1] = make_float4(acc[4], acc[5], acc[6], acc[7]);
}

extern "C" void kernel_launch(void* const* d_in, const int* in_sizes, int n_in,
                              void* d_out, int out_size, void* d_ws, size_t ws_size,
                              hipStream_t stream) {
    const float* mz   = (const float*)d_in[0];
    const float* pi_l = (const float*)d_in[1];
    const float* mu   = (const float*)d_in[2];
    const float* lv   = (const float*)d_in[3];
    float* out = (float*)d_out;
    float4* params = (float4*)d_ws;      // 128 * 16 B = 2 KB scratch
    int n = in_sizes[0];                 // 4,194,304

    gmm_prep<<<1, 64, 0, stream>>>(pi_l, mu, lv, params);

    int threads = n / 8;                 // 8 points per thread
    int block = 256;
    int grid = (threads + block - 1) / block;
    gmm_main<<<grid, block, 0, stream>>>(mz, params, out, n);
}

// Round 2
// 90.754 us; speedup vs baseline: 1.5879x; 1.5879x over previous
//
#include <hip/hip_runtime.h>
#include <math.h>

#define K_COMP 128
#define LOG2E 1.4426950408889634f
#define INV_SQRT_2PI 0.3989422804014327f
#define PPT 16          // points per thread
#define BLOCK 256
#define WRAD 5          // window radius (components), window = 12 wide
#define WWIN 12

// Fused: per-block prep (softmax + param transform + window-safety check) in
// wave 0, then windowed evaluation. prob[n] = sum_k exp2(A_k (x-mu_k)^2 + lc_k)
// Window path requires (derived at runtime from actual params):
//   - all A_k identical (uniform variance)
//   - max_k [ |mu_k*127 - k| + 127*cutoff_dist_k ] + 0.5 <= WRAD
// else falls back to the full 128-component loop (always correct).
__global__ __launch_bounds__(BLOCK) void gmm_fused(const float* __restrict__ mz,
                                                   const float* __restrict__ pi_l,
                                                   const float* __restrict__ mu,
                                                   const float* __restrict__ lv,
                                                   float* __restrict__ out,
                                                   int n) {
    __shared__ float2 sp2[K_COMP];   // {mu, lc} for window path
    __shared__ float4 sp4[K_COMP];   // {mu, A, lc, 0} for fallback path
    __shared__ float sA;
    __shared__ int sWin;

    int tid = threadIdx.x;

    if (tid < 64) {
        int t = tid;
        float p0 = pi_l[t];
        float p1 = pi_l[t + 64];
        float m = fmaxf(p0, p1);
        #pragma unroll
        for (int off = 1; off < 64; off <<= 1)
            m = fmaxf(m, __shfl_xor(m, off, 64));
        float e0 = expf(p0 - m);
        float e1 = expf(p1 - m);
        float s = e0 + e1;
        #pragma unroll
        for (int off = 1; off < 64; off <<= 1)
            s += __shfl_xor(s, off, 64);
        float inv_s = 1.0f / s;

        float rad = 0.0f, amin = 1e30f, amax = -1e30f;
        #pragma unroll
        for (int j = 0; j < 2; j++) {
            int k = t + 64 * j;
            float e = (j == 0) ? e0 : e1;
            float pi_k = e * inv_s;
            float lvk = lv[k];
            float A = -0.5f * expf(-lvk) * LOG2E;              // < 0 always
            float coef = pi_k * INV_SQRT_2PI * expf(-0.5f * lvk);
            float lc = log2f(coef);                            // -inf ok
            float muk = mu[k];
            sp4[k] = make_float4(muk, A, lc, 0.0f);
            sp2[k] = make_float2(muk, lc);
            // cutoff distance: contribution < 2^-30 beyond it
            float num = fmaxf(lc + 30.0f, 0.0f);
            float dk = sqrtf(num / (-A));                      // A<0
            float r = fabsf(muk * 127.0f - (float)k) + dk * 127.0f;
            rad = fmaxf(rad, r);
            amin = fminf(amin, A);
            amax = fmaxf(amax, A);
        }
        #pragma unroll
        for (int off = 1; off < 64; off <<= 1) {
            rad = fmaxf(rad, __shfl_xor(rad, off, 64));
            amin = fminf(amin, __shfl_xor(amin, off, 64));
            amax = fmaxf(amax, __shfl_xor(amax, off, 64));
        }
        if (t == 0) {
            sA = amax;
            sWin = (amin == amax && rad + 0.5f <= (float)WRAD) ? 1 : 0;
        }
    }
    __syncthreads();

    const float A = sA;
    const int win = sWin;
    long blockBase = (long)blockIdx.x * (BLOCK * PPT);

    float x[PPT];
    #pragma unroll
    for (int p = 0; p < PPT; p++) {
        long idx = blockBase + (long)p * BLOCK + tid;
        x[p] = (idx < n) ? mz[idx] : 0.0f;
    }

    float acc[PPT];
    if (win) {
        #pragma unroll
        for (int p = 0; p < PPT; p++) {
            float xp = x[p];
            int kc = (int)fmaf(xp, 127.0f, 0.5f);
            int k0 = min(max(kc - WRAD, 0), K_COMP - WWIN);
            float a = 0.0f;
            #pragma unroll
            for (int j = 0; j < WWIN; j++) {
                float2 pr = sp2[k0 + j];                       // per-lane gather
                float d = xp - pr.x;
                float t = __builtin_fmaf(d * A, d, pr.y);
                a += __builtin_amdgcn_exp2f(t);
            }
            acc[p] = a;
        }
    } else {
        #pragma unroll
        for (int p = 0; p < PPT; p++) acc[p] = 0.0f;
        for (int k = 0; k < K_COMP; k++) {
            float4 pr = sp4[k];                                // broadcast
            #pragma unroll
            for (int p = 0; p < PPT; p++) {
                float d = x[p] - pr.x;
                float t = __builtin_fmaf(d * pr.y, d, pr.z);
                acc[p] += __builtin_amdgcn_exp2f(t);
            }
        }
    }

    #pragma unroll
    for (int p = 0; p < PPT; p++) {
        long idx = blockBase + (long)p * BLOCK + tid;
        if (idx < n) out[idx] = acc[p];
    }
}

extern "C" void kernel_launch(void* const* d_in, const int* in_sizes, int n_in,
                              void* d_out, int out_size, void* d_ws, size_t ws_size,
                              hipStream_t stream) {
    const float* mz   = (const float*)d_in[0];
    const float* pi_l = (const float*)d_in[1];
    const float* mu   = (const float*)d_in[2];
    const float* lv   = (const float*)d_in[3];
    float* out = (float*)d_out;
    int n = in_sizes[0];                 // 4,194,304

    int grid = (n + BLOCK * PPT - 1) / (BLOCK * PPT);   // 1024
    gmm_fused<<<grid, BLOCK, 0, stream>>>(mz, pi_l, mu, lv, out, n);
}

// Round 3
// 86.854 us; speedup vs baseline: 1.6593x; 1.0449x over previous
//
#include <hip/hip_runtime.h>
#include <math.h>

#define K_COMP 128
#define LOG2E 1.4426950408889634f
#define INV_SQRT_2PI 0.3989422804014327f
#define PPT 16          // points per thread
#define BLOCK 256
#define WRAD 5          // window radius (components)
#define WWIN 12         // window width
#define REP 32          // replicas per row (one per bank)
#define ROW 64          // floats per row: [mu x32 | lc x32]

// prob[n] = sum_k exp2( A_k (x-mu_k)^2 + lc_k ),  A_k = -0.5 exp(-lv_k) log2e,
// lc_k = log2( softmax(pi)_k * inv_sqrt_2pi * exp(-lv_k/2) ).
// Window path (runtime-verified): uniform A, window kc±WRAD covers all
// contributions > 2^-30. Param table is bank-replicated: lane l always reads
// bank l&31 -> worst case 2-way aliasing (free), all window reads share one
// base register + immediate offsets.
__global__ __launch_bounds__(BLOCK) void gmm_fused(const float* __restrict__ mz,
                                                   const float* __restrict__ pi_l,
                                                   const float* __restrict__ mu,
                                                   const float* __restrict__ lv,
                                                   float* __restrict__ out,
                                                   int n) {
    __shared__ float sp[K_COMP * ROW];   // 32 KB replicated {mu,lc}
    __shared__ float4 sRaw[K_COMP];      // staging: {mu, A, lc, 0}
    __shared__ float sAk[K_COMP];        // per-k A for fallback
    __shared__ float sAs;
    __shared__ int sWin;

    int tid = threadIdx.x;

    // ---- phase 1: wave 0 computes transformed params + window check ----
    if (tid < 64) {
        int t = tid;
        float p0 = pi_l[t];
        float p1 = pi_l[t + 64];
        float m = fmaxf(p0, p1);
        #pragma unroll
        for (int off = 1; off < 64; off <<= 1)
            m = fmaxf(m, __shfl_xor(m, off, 64));
        float e0 = expf(p0 - m);
        float e1 = expf(p1 - m);
        float s = e0 + e1;
        #pragma unroll
        for (int off = 1; off < 64; off <<= 1)
            s += __shfl_xor(s, off, 64);
        float inv_s = 1.0f / s;

        float rad = 0.0f, amin = 1e30f, amax = -1e30f;
        #pragma unroll
        for (int j = 0; j < 2; j++) {
            int k = t + 64 * j;
            float e = (j == 0) ? e0 : e1;
            float pi_k = e * inv_s;
            float lvk = lv[k];
            float A = -0.5f * expf(-lvk) * LOG2E;              // < 0
            float coef = pi_k * INV_SQRT_2PI * expf(-0.5f * lvk);
            float lc = log2f(coef);                            // -inf ok
            float muk = mu[k];
            sRaw[k] = make_float4(muk, A, lc, 0.0f);
            float num = fmaxf(lc + 30.0f, 0.0f);               // 2^-30 cutoff
            float dk = sqrtf(num / (-A));
            float r = fabsf(muk * 127.0f - (float)k) + dk * 127.0f;
            rad = fmaxf(rad, r);
            amin = fminf(amin, A);
            amax = fmaxf(amax, A);
        }
        #pragma unroll
        for (int off = 1; off < 64; off <<= 1) {
            rad = fmaxf(rad, __shfl_xor(rad, off, 64));
            amin = fminf(amin, __shfl_xor(amin, off, 64));
            amax = fmaxf(amax, __shfl_xor(amax, off, 64));
        }
        if (t == 0) {
            sAs = amax;
            sWin = (amin == amax && rad + 0.5f <= (float)WRAD) ? 1 : 0;
        }
    }
    __syncthreads();

    // ---- phase 2: all 256 threads build the bank-replicated table ----
    {
        int k = tid >> 1;
        int half = tid & 1;                  // 0 -> mu region, 1 -> lc region
        float4 r = sRaw[k];
        float v = half ? r.z : r.x;
        float4 vv = make_float4(v, v, v, v);
        float4* dst = (float4*)&sp[k * ROW + half * REP];
        #pragma unroll
        for (int i = 0; i < 8; i++) dst[i] = vv;
        if (!half) sAk[k] = r.y;
    }
    __syncthreads();

    const float A = sAs;
    const int win = sWin;
    const int lrep = tid & (REP - 1);
    long blockBase = (long)blockIdx.x * (BLOCK * PPT);

    float x[PPT];
    #pragma unroll
    for (int p = 0; p < PPT; p++) {
        long idx = blockBase + (long)p * BLOCK + tid;
        x[p] = (idx < n) ? mz[idx] : 0.0f;
    }

    float acc[PPT];
    if (win) {
        #pragma unroll
        for (int p = 0; p < PPT; p++) {
            float xp = x[p];
            int kc = (int)__builtin_fmaf(xp, 127.0f, 0.5f);
            int k0 = min(max(kc - WRAD, 0), K_COMP - WWIN);
            const float* row = &sp[(k0 << 6) + lrep];
            float mv[WWIN], cv[WWIN];
            #pragma unroll
            for (int j = 0; j < WWIN; j++) {          // 24 x ds_read_b32,
                mv[j] = row[j * ROW];                 // one base + imm offsets,
                cv[j] = row[j * ROW + REP];           // bank = lane&31 always
            }
            float a = 0.0f;
            #pragma unroll
            for (int j = 0; j < WWIN; j++) {
                float d = xp - mv[j];
                float t = __builtin_fmaf(d * A, d, cv[j]);
                a += __builtin_amdgcn_exp2f(t);
            }
            acc[p] = a;
        }
    } else {
        #pragma unroll
        for (int p = 0; p < PPT; p++) acc[p] = 0.0f;
        for (int k = 0; k < K_COMP; k++) {
            float mk = sp[(k << 6) + lrep];           // per-lane replica, free
            float ck = sp[(k << 6) + REP + lrep];
            float Ak = sAk[k];
            #pragma unroll
            for (int p = 0; p < PPT; p++) {
                float d = x[p] - mk;
                float t = __builtin_fmaf(d * Ak, d, ck);
                acc[p] += __builtin_amdgcn_exp2f(t);
            }
        }
    }

    #pragma unroll
    for (int p = 0; p < PPT; p++) {
        long idx = blockBase + (long)p * BLOCK + tid;
        if (idx < n) out[idx] = acc[p];
    }
}

extern "C" void kernel_launch(void* const* d_in, const int* in_sizes, int n_in,
                              void* d_out, int out_size, void* d_ws, size_t ws_size,
                              hipStream_t stream) {
    const float* mz   = (const float*)d_in[0];
    const float* pi_l = (const float*)d_in[1];
    const float* mu   = (const float*)d_in[2];
    const float* lv   = (const float*)d_in[3];
    float* out = (float*)d_out;
    int n = in_sizes[0];                 // 4,194,304

    int grid = (n + BLOCK * PPT - 1) / (BLOCK * PPT);   // 1024
    gmm_fused<<<grid, BLOCK, 0, stream>>>(mz, pi_l, mu, lv, out, n);
}

// Round 4
// 84.820 us; speedup vs baseline: 1.6990x; 1.0240x over previous
//
#include <hip/hip_runtime.h>
#include <math.h>

#define K_COMP 128
#define LOG2E 1.4426950408889634f
#define INV_SQRT_2PI 0.3989422804014327f
#define PPT 16          // points per thread
#define BLOCK 256
#define WRAD 5          // window radius (components)
#define WWIN 12         // window width
#define REP 32          // float2 replicas per row (bank-spread)

// prob[n] = sum_k exp2( A_k (x-mu_k)^2 + lc_k ),  A_k = -0.5 exp(-lv_k) log2e,
// lc_k = log2( softmax(pi)_k * inv_sqrt_2pi * exp(-lv_k/2) ).
// Window path (runtime-verified): uniform A, window kc+-WRAD covers all
// contributions > 2^-30; else full-128 fallback (always correct).
// {mu,lc} stored as adjacent float2 -> ONE ds_read_b64 per (point,k);
// 32 replicas/row -> lane l reads banks 2(l&31),2(l&31)+1 -> <=2 addr/bank.
__global__ __launch_bounds__(BLOCK) void gmm_fused(const float* __restrict__ mz,
                                                   const float* __restrict__ pi_l,
                                                   const float* __restrict__ mu,
                                                   const float* __restrict__ lv,
                                                   float* __restrict__ out,
                                                   int n) {
    __shared__ float2 sp[K_COMP * REP];  // 32 KB replicated {mu, lc}
    __shared__ float4 sRaw[K_COMP];      // {mu, A, lc, 0} (kept for fallback)
    __shared__ float sAs;
    __shared__ int sWin;

    int tid = threadIdx.x;

    // ---- phase 1: wave 0 computes transformed params + window check ----
    if (tid < 64) {
        int t = tid;
        float p0 = pi_l[t];
        float p1 = pi_l[t + 64];
        float m = fmaxf(p0, p1);
        #pragma unroll
        for (int off = 1; off < 64; off <<= 1)
            m = fmaxf(m, __shfl_xor(m, off, 64));
        float e0 = expf(p0 - m);
        float e1 = expf(p1 - m);
        float s = e0 + e1;
        #pragma unroll
        for (int off = 1; off < 64; off <<= 1)
            s += __shfl_xor(s, off, 64);
        float inv_s = 1.0f / s;

        float rad = 0.0f, amin = 1e30f, amax = -1e30f;
        #pragma unroll
        for (int j = 0; j < 2; j++) {
            int k = t + 64 * j;
            float e = (j == 0) ? e0 : e1;
            float pi_k = e * inv_s;
            float lvk = lv[k];
            float A = -0.5f * expf(-lvk) * LOG2E;              // < 0
            float coef = pi_k * INV_SQRT_2PI * expf(-0.5f * lvk);
            float lc = log2f(coef);                            // -inf ok
            float muk = mu[k];
            sRaw[k] = make_float4(muk, A, lc, 0.0f);
            float num = fmaxf(lc + 30.0f, 0.0f);               // 2^-30 cutoff
            float dk = sqrtf(num / (-A));
            float r = fabsf(muk * 127.0f - (float)k) + dk * 127.0f;
            rad = fmaxf(rad, r);
            amin = fminf(amin, A);
            amax = fmaxf(amax, A);
        }
        #pragma unroll
        for (int off = 1; off < 64; off <<= 1) {
            rad = fmaxf(rad, __shfl_xor(rad, off, 64));
            amin = fminf(amin, __shfl_xor(amin, off, 64));
            amax = fmaxf(amax, __shfl_xor(amax, off, 64));
        }
        if (t == 0) {
            sAs = amax;
            sWin = (amin == amax && rad + 0.5f <= (float)WRAD) ? 1 : 0;
        }
    }
    __syncthreads();

    // ---- phase 2: all 256 threads build replicated table, bank-spread ----
    // thread -> replica r = tid&31, rows k = (tid>>5)*16 + i. Within a wave,
    // lanes cover replicas 0..31 twice -> <=2 addr/bank per write phase.
    {
        int r = tid & 31;
        int kb = (tid >> 5) << 4;            // 0,16,...,112
        #pragma unroll
        for (int i = 0; i < 16; i++) {
            int k = kb + i;
            float4 raw = sRaw[k];            // broadcast read (free)
            sp[(k << 5) + r] = make_float2(raw.x, raw.z);
        }
    }
    __syncthreads();

    const float A = sAs;
    const int win = sWin;
    const int lrep = tid & (REP - 1);
    long blockBase = (long)blockIdx.x * (BLOCK * PPT);

    // float4 global loads: group g holds points blockBase + (g*BLOCK+tid)*4 ..+3
    const float4* mz4 = (const float4*)mz;
    long base4 = blockBase >> 2;
    float x[PPT];
    #pragma unroll
    for (int g = 0; g < PPT / 4; g++) {
        float4 v = mz4[base4 + (long)g * BLOCK + tid];
        x[g * 4 + 0] = v.x; x[g * 4 + 1] = v.y;
        x[g * 4 + 2] = v.z; x[g * 4 + 3] = v.w;
    }

    float acc[PPT];
    if (win) {
        #pragma unroll
        for (int p = 0; p < PPT; p++) {
            float xp = x[p];
            int kc = (int)__builtin_fmaf(xp, 127.0f, 0.5f);
            int k0 = min(max(kc - WRAD, 0), K_COMP - WWIN);
            const float2* row = &sp[(k0 << 5) + lrep];
            float2 pr[WWIN];
            #pragma unroll
            for (int j = 0; j < WWIN; j++)
                pr[j] = row[j << 5];         // ds_read_b64, imm offset j*256B
            float a = 0.0f;
            #pragma unroll
            for (int j = 0; j < WWIN; j++) {
                float d = xp - pr[j].x;
                float t = __builtin_fmaf(d * A, d, pr[j].y);
                a += __builtin_amdgcn_exp2f(t);
            }
            acc[p] = a;
        }
    } else {
        #pragma unroll
        for (int p = 0; p < PPT; p++) acc[p] = 0.0f;
        for (int k = 0; k < K_COMP; k++) {
            float4 raw = sRaw[k];            // broadcast (free)
            #pragma unroll
            for (int p = 0; p < PPT; p++) {
                float d = x[p] - raw.x;
                float t = __builtin_fmaf(d * raw.y, d, raw.z);
                acc[p] += __builtin_amdgcn_exp2f(t);
            }
        }
    }

    float4* out4 = (float4*)out;
    #pragma unroll
    for (int g = 0; g < PPT / 4; g++) {
        float4 v = make_float4(acc[g * 4 + 0], acc[g * 4 + 1],
                               acc[g * 4 + 2], acc[g * 4 + 3]);
        out4[base4 + (long)g * BLOCK + tid] = v;
    }
}

extern "C" void kernel_launch(void* const* d_in, const int* in_sizes, int n_in,
                              void* d_out, int out_size, void* d_ws, size_t ws_size,
                              hipStream_t stream) {
    const float* mz   = (const float*)d_in[0];
    const float* pi_l = (const float*)d_in[1];
    const float* mu   = (const float*)d_in[2];
    const float* lv   = (const float*)d_in[3];
    float* out = (float*)d_out;
    int n = in_sizes[0];                 // 4,194,304 (multiple of BLOCK*PPT)

    int grid = (n + BLOCK * PPT - 1) / (BLOCK * PPT);   // 1024
    gmm_fused<<<grid, BLOCK, 0, stream>>>(mz, pi_l, mu, lv, out, n);
}

// Round 5
// 79.411 us; speedup vs baseline: 1.8148x; 1.0681x over previous
//
#include <hip/hip_runtime.h>
#include <math.h>

#define K_COMP 128
#define LOG2E 1.4426950408889634f
#define INV_SQRT_2PI 0.3989422804014327f
#define PPT 16          // points per thread
#define BLOCK 256
#define REP 32          // scalar replicas per row (one per bank)

// prob[n] = sum_k exp2( A_k (x-mu_k)^2 + lc_k ),  A_k = -0.5 exp(-lv_k) log2e,
// lc_k = log2( softmax(pi)_k * inv_sqrt_2pi * exp(-lv_k/2) ).
// Three runtime-selected paths (checks derived from ACTUAL params):
//   win=2: 8-wide window, cutoff 2^-12, k0 = floor(x*127)-3  (R <= 3.0)
//   win=1: 12-wide window, cutoff 2^-30, k0 = floor(x*127)-5 (R <= 5.0)
//   win=0: full 128-component loop (always correct)
// Tables are scalar-split and bank-replicated: smu/slc[k*32 + (lane&31)]
// -> ds_read_b32 always hits bank lane&31, worst 2-way alias = free.

template <int W, int OFF>
__device__ __forceinline__ void eval_window(const float* __restrict__ smu,
                                            const float* __restrict__ slc,
                                            int lrep, float A,
                                            const float* x, float* acc) {
    #pragma unroll
    for (int p = 0; p < PPT; p++) {
        float xp = x[p];
        float t127 = xp * 127.0f;
        int k0 = min(max((int)t127 - OFF, 0), K_COMP - W);
        const float* mrow = &smu[(k0 << 5) + lrep];
        const float* crow = &slc[(k0 << 5) + lrep];
        float mv[W], cv[W];
        #pragma unroll
        for (int j = 0; j < W; j++) {          // ds_read_b32, imm offset j*128B
            mv[j] = mrow[j << 5];
            cv[j] = crow[j << 5];
        }
        float a0 = 0.0f, a1 = 0.0f;
        #pragma unroll
        for (int j = 0; j < W; j += 2) {
            float d0 = xp - mv[j];
            a0 += __builtin_amdgcn_exp2f(__builtin_fmaf(d0 * A, d0, cv[j]));
            float d1 = xp - mv[j + 1];
            a1 += __builtin_amdgcn_exp2f(__builtin_fmaf(d1 * A, d1, cv[j + 1]));
        }
        acc[p] = a0 + a1;
    }
}

__global__ __launch_bounds__(BLOCK) void gmm_fused(const float* __restrict__ mz,
                                                   const float* __restrict__ pi_l,
                                                   const float* __restrict__ mu,
                                                   const float* __restrict__ lv,
                                                   float* __restrict__ out,
                                                   int n) {
    __shared__ float smu[K_COMP * REP];  // 16 KB replicated mu
    __shared__ float slc[K_COMP * REP];  // 16 KB replicated lc
    __shared__ float4 sRaw[K_COMP];      // {mu, A, lc, 0} for fallback
    __shared__ float sAs;
    __shared__ int sWin;

    int tid = threadIdx.x;

    // ---- phase 1: wave 0 computes transformed params + window checks ----
    if (tid < 64) {
        int t = tid;
        float p0 = pi_l[t];
        float p1 = pi_l[t + 64];
        float m = fmaxf(p0, p1);
        #pragma unroll
        for (int off = 1; off < 64; off <<= 1)
            m = fmaxf(m, __shfl_xor(m, off, 64));
        float e0 = expf(p0 - m);
        float e1 = expf(p1 - m);
        float s = e0 + e1;
        #pragma unroll
        for (int off = 1; off < 64; off <<= 1)
            s += __shfl_xor(s, off, 64);
        float inv_s = 1.0f / s;

        float r12 = 0.0f, r30 = 0.0f, amin = 1e30f, amax = -1e30f;
        #pragma unroll
        for (int j = 0; j < 2; j++) {
            int k = t + 64 * j;
            float e = (j == 0) ? e0 : e1;
            float pi_k = e * inv_s;
            float lvk = lv[k];
            float A = -0.5f * expf(-lvk) * LOG2E;              // < 0
            float coef = pi_k * INV_SQRT_2PI * expf(-0.5f * lvk);
            float lc = log2f(coef);                            // -inf ok
            float muk = mu[k];
            sRaw[k] = make_float4(muk, A, lc, 0.0f);
            float del = fabsf(muk * 127.0f - (float)k);
            float d12 = sqrtf(fmaxf(lc + 12.0f, 0.0f) / (-A)) * 127.0f;
            float d30 = sqrtf(fmaxf(lc + 30.0f, 0.0f) / (-A)) * 127.0f;
            r12 = fmaxf(r12, del + d12);
            r30 = fmaxf(r30, del + d30);
            amin = fminf(amin, A);
            amax = fmaxf(amax, A);
        }
        #pragma unroll
        for (int off = 1; off < 64; off <<= 1) {
            r12 = fmaxf(r12, __shfl_xor(r12, off, 64));
            r30 = fmaxf(r30, __shfl_xor(r30, off, 64));
            amin = fminf(amin, __shfl_xor(amin, off, 64));
            amax = fmaxf(amax, __shfl_xor(amax, off, 64));
        }
        if (t == 0) {
            sAs = amax;
            int w = 0;
            if (amin == amax) {
                if (r12 <= 3.0f)      w = 2;   // 8-window, floor-center +-3
                else if (r30 <= 5.0f) w = 1;   // 12-window, floor-center +-5
            }
            sWin = w;
        }
    }
    __syncthreads();

    // ---- phase 2: build split bank-replicated tables ----
    {
        int r = tid & 31;
        int kb = (tid >> 5) << 4;            // 0,16,...,112
        #pragma unroll
        for (int i = 0; i < 16; i++) {
            int k = kb + i;
            float4 raw = sRaw[k];            // broadcast read (free)
            smu[(k << 5) + r] = raw.x;       // write bank = lane&31, 2-way
            slc[(k << 5) + r] = raw.z;
        }
    }
    __syncthreads();

    const float A = sAs;
    const int win = sWin;
    const int lrep = tid & (REP - 1);
    long blockBase = (long)blockIdx.x * (BLOCK * PPT);

    const float4* mz4 = (const float4*)mz;
    long base4 = blockBase >> 2;
    float x[PPT];
    #pragma unroll
    for (int g = 0; g < PPT / 4; g++) {
        float4 v = mz4[base4 + (long)g * BLOCK + tid];
        x[g * 4 + 0] = v.x; x[g * 4 + 1] = v.y;
        x[g * 4 + 2] = v.z; x[g * 4 + 3] = v.w;
    }

    float acc[PPT];
    if (win == 2) {
        eval_window<8, 3>(smu, slc, lrep, A, x, acc);
    } else if (win == 1) {
        eval_window<12, 5>(smu, slc, lrep, A, x, acc);
    } else {
        #pragma unroll
        for (int p = 0; p < PPT; p++) acc[p] = 0.0f;
        for (int k = 0; k < K_COMP; k++) {
            float4 raw = sRaw[k];            // broadcast (free)
            #pragma unroll
            for (int p = 0; p < PPT; p++) {
                float d = x[p] - raw.x;
                float t = __builtin_fmaf(d * raw.y, d, raw.z);
                acc[p] += __builtin_amdgcn_exp2f(t);
            }
        }
    }

    float4* out4 = (float4*)out;
    #pragma unroll
    for (int g = 0; g < PPT / 4; g++) {
        float4 v = make_float4(acc[g * 4 + 0], acc[g * 4 + 1],
                               acc[g * 4 + 2], acc[g * 4 + 3]);
        out4[base4 + (long)g * BLOCK + tid] = v;
    }
}

extern "C" void kernel_launch(void* const* d_in, const int* in_sizes, int n_in,
                              void* d_out, int out_size, void* d_ws, size_t ws_size,
                              hipStream_t stream) {
    const float* mz   = (const float*)d_in[0];
    const float* pi_l = (const float*)d_in[1];
    const float* mu   = (const float*)d_in[2];
    const float* lv   = (const float*)d_in[3];
    float* out = (float*)d_out;
    int n = in_sizes[0];                 // 4,194,304 (multiple of BLOCK*PPT)

    int grid = (n + BLOCK * PPT - 1) / (BLOCK * PPT);   // 1024
    gmm_fused<<<grid, BLOCK, 0, stream>>>(mz, pi_l, mu, lv, out, n);
}

// Round 6
// 78.546 us; speedup vs baseline: 1.8348x; 1.0110x over previous
//
#include <hip/hip_runtime.h>
#include <math.h>

#define K_COMP 128
#define LOG2E 1.4426950408889634f
#define INV_SQRT_2PI 0.3989422804014327f
#define PPT 16          // points per thread
#define BLOCK 256
#define REP 32          // scalar replicas per row (one per bank)

// prob[n] = sum_k exp2( A_k (x-mu_k)^2 + lc_k ),  A_k = -0.5 exp(-lv_k) log2e,
// lc_k = log2( softmax(pi)_k * inv_sqrt_2pi * exp(-lv_k/2) ).
// Runtime-selected paths (checks derived from ACTUAL params, never assumed):
//   win=3: uniform A AND uniform lc AND 8-window safe ->
//          prob = 2^lc * sum exp2(A d^2), gather mu ONLY (8 ds_read_b32/pt)
//   win=2: uniform A, 8-window safe -> gather {mu, lc} (16 reads/pt)
//   win=1: uniform A, 12-window safe (2^-30 cutoff)
//   win=0: full 128-component loop (always correct)
// Tables bank-replicated: s[k*32 + (lane&31)] -> bank = lane&31 always,
// worst alias 2-way (lane l vs l+32) = free (m136).

template <int W, int OFF>
__device__ __forceinline__ void eval_mu_only(const float* __restrict__ smu,
                                             int lrep, float A, float scale,
                                             const float* x, float* acc) {
    #pragma unroll
    for (int p = 0; p < PPT; p++) {
        float xp = x[p];
        int k0 = min(max((int)(xp * 127.0f) - OFF, 0), K_COMP - W);
        const float* mrow = &smu[(k0 << 5) + lrep];
        float mv[W];
        #pragma unroll
        for (int j = 0; j < W; j++)
            mv[j] = mrow[j << 5];            // ds_read_b32, imm offset j*128B
        float a0 = 0.0f, a1 = 0.0f;
        #pragma unroll
        for (int j = 0; j < W; j += 2) {
            float d0 = xp - mv[j];
            a0 += __builtin_amdgcn_exp2f(d0 * A * d0);
            float d1 = xp - mv[j + 1];
            a1 += __builtin_amdgcn_exp2f(d1 * A * d1);
        }
        acc[p] = (a0 + a1) * scale;
    }
}

template <int W, int OFF>
__device__ __forceinline__ void eval_window(const float* __restrict__ smu,
                                            const float* __restrict__ slc,
                                            int lrep, float A,
                                            const float* x, float* acc) {
    #pragma unroll
    for (int p = 0; p < PPT; p++) {
        float xp = x[p];
        int k0 = min(max((int)(xp * 127.0f) - OFF, 0), K_COMP - W);
        const float* mrow = &smu[(k0 << 5) + lrep];
        const float* crow = &slc[(k0 << 5) + lrep];
        float mv[W], cv[W];
        #pragma unroll
        for (int j = 0; j < W; j++) {
            mv[j] = mrow[j << 5];
            cv[j] = crow[j << 5];
        }
        float a0 = 0.0f, a1 = 0.0f;
        #pragma unroll
        for (int j = 0; j < W; j += 2) {
            float d0 = xp - mv[j];
            a0 += __builtin_amdgcn_exp2f(__builtin_fmaf(d0 * A, d0, cv[j]));
            float d1 = xp - mv[j + 1];
            a1 += __builtin_amdgcn_exp2f(__builtin_fmaf(d1 * A, d1, cv[j + 1]));
        }
        acc[p] = a0 + a1;
    }
}

__global__ __launch_bounds__(BLOCK) void gmm_fused(const float* __restrict__ mz,
                                                   const float* __restrict__ pi_l,
                                                   const float* __restrict__ mu,
                                                   const float* __restrict__ lv,
                                                   float* __restrict__ out,
                                                   int n) {
    __shared__ float smu[K_COMP * REP];  // 16 KB replicated mu
    __shared__ float slc[K_COMP * REP];  // 16 KB replicated lc (win==2 only)
    __shared__ float4 sRaw[K_COMP];      // {mu, A, lc, 0} for fallback
    __shared__ float sAs, sScale;
    __shared__ int sWin;

    int tid = threadIdx.x;

    // ---- phase 1: wave 0 computes transformed params + path checks ----
    if (tid < 64) {
        int t = tid;
        float p0 = pi_l[t];
        float p1 = pi_l[t + 64];
        float m = fmaxf(p0, p1);
        #pragma unroll
        for (int off = 1; off < 64; off <<= 1)
            m = fmaxf(m, __shfl_xor(m, off, 64));
        float e0 = expf(p0 - m);
        float e1 = expf(p1 - m);
        float s = e0 + e1;
        #pragma unroll
        for (int off = 1; off < 64; off <<= 1)
            s += __shfl_xor(s, off, 64);
        float inv_s = 1.0f / s;

        float r12 = 0.0f, r30 = 0.0f;
        float amin = 1e30f, amax = -1e30f;
        float lmin = 1e30f, lmax = -1e30f;
        #pragma unroll
        for (int j = 0; j < 2; j++) {
            int k = t + 64 * j;
            float e = (j == 0) ? e0 : e1;
            float pi_k = e * inv_s;
            float lvk = lv[k];
            float A = -0.5f * expf(-lvk) * LOG2E;              // < 0
            float coef = pi_k * INV_SQRT_2PI * expf(-0.5f * lvk);
            float lc = log2f(coef);                            // -inf ok
            float muk = mu[k];
            sRaw[k] = make_float4(muk, A, lc, 0.0f);
            float del = fabsf(muk * 127.0f - (float)k);
            float d12 = sqrtf(fmaxf(lc + 12.0f, 0.0f) / (-A)) * 127.0f;
            float d30 = sqrtf(fmaxf(lc + 30.0f, 0.0f) / (-A)) * 127.0f;
            r12 = fmaxf(r12, del + d12);
            r30 = fmaxf(r30, del + d30);
            amin = fminf(amin, A);  amax = fmaxf(amax, A);
            lmin = fminf(lmin, lc); lmax = fmaxf(lmax, lc);
        }
        #pragma unroll
        for (int off = 1; off < 64; off <<= 1) {
            r12 = fmaxf(r12, __shfl_xor(r12, off, 64));
            r30 = fmaxf(r30, __shfl_xor(r30, off, 64));
            amin = fminf(amin, __shfl_xor(amin, off, 64));
            amax = fmaxf(amax, __shfl_xor(amax, off, 64));
            lmin = fminf(lmin, __shfl_xor(lmin, off, 64));
            lmax = fmaxf(lmax, __shfl_xor(lmax, off, 64));
        }
        if (t == 0) {
            sAs = amax;
            sScale = __builtin_amdgcn_exp2f(lmax);
            int w = 0;
            if (amin == amax) {
                if (r12 <= 3.0f)      w = (lmin == lmax) ? 3 : 2;
                else if (r30 <= 5.0f) w = 1;
            }
            sWin = w;
        }
    }
    __syncthreads();

    const int win = sWin;

    // ---- phase 2: build bank-replicated tables (lc table only if needed) ----
    {
        int r = tid & 31;
        int kb = (tid >> 5) << 4;            // 0,16,...,112
        if (win == 3) {
            #pragma unroll
            for (int i = 0; i < 16; i++) {
                int k = kb + i;
                smu[(k << 5) + r] = sRaw[k].x;   // bank = lane&31, 2-way free
            }
        } else {
            #pragma unroll
            for (int i = 0; i < 16; i++) {
                int k = kb + i;
                float4 raw = sRaw[k];
                smu[(k << 5) + r] = raw.x;
                slc[(k << 5) + r] = raw.z;
            }
        }
    }
    __syncthreads();

    const float A = sAs;
    const float scale = sScale;
    const int lrep = tid & (REP - 1);
    long blockBase = (long)blockIdx.x * (BLOCK * PPT);

    const float4* mz4 = (const float4*)mz;
    long base4 = blockBase >> 2;
    float x[PPT];
    #pragma unroll
    for (int g = 0; g < PPT / 4; g++) {
        float4 v = mz4[base4 + (long)g * BLOCK + tid];
        x[g * 4 + 0] = v.x; x[g * 4 + 1] = v.y;
        x[g * 4 + 2] = v.z; x[g * 4 + 3] = v.w;
    }

    float acc[PPT];
    if (win == 3) {
        eval_mu_only<8, 3>(smu, lrep, A, scale, x, acc);
    } else if (win == 2) {
        eval_window<8, 3>(smu, slc, lrep, A, x, acc);
    } else if (win == 1) {
        eval_window<12, 5>(smu, slc, lrep, A, x, acc);
    } else {
        #pragma unroll
        for (int p = 0; p < PPT; p++) acc[p] = 0.0f;
        for (int k = 0; k < K_COMP; k++) {
            float4 raw = sRaw[k];            // broadcast (free)
            #pragma unroll
            for (int p = 0; p < PPT; p++) {
                float d = x[p] - raw.x;
                float t = __builtin_fmaf(d * raw.y, d, raw.z);
                acc[p] += __builtin_amdgcn_exp2f(t);
            }
        }
    }

    float4* out4 = (float4*)out;
    #pragma unroll
    for (int g = 0; g < PPT / 4; g++) {
        float4 v = make_float4(acc[g * 4 + 0], acc[g * 4 + 1],
                               acc[g * 4 + 2], acc[g * 4 + 3]);
        out4[base4 + (long)g * BLOCK + tid] = v;
    }
}

extern "C" void kernel_launch(void* const* d_in, const int* in_sizes, int n_in,
                              void* d_out, int out_size, void* d_ws, size_t ws_size,
                              hipStream_t stream) {
    const float* mz   = (const float*)d_in[0];
    const float* pi_l = (const float*)d_in[1];
    const float* mu   = (const float*)d_in[2];
    const float* lv   = (const float*)d_in[3];
    float* out = (float*)d_out;
    int n = in_sizes[0];                 // 4,194,304 (multiple of BLOCK*PPT)

    int grid = (n + BLOCK * PPT - 1) / (BLOCK * PPT);   // 1024
    gmm_fused<<<grid, BLOCK, 0, stream>>>(mz, pi_l, mu, lv, out, n);
}